// Round 6
// baseline (162.374 us; speedup 1.0000x reference)
//
#include <hip/hip_runtime.h>
#include <hip/hip_bf16.h>

namespace {

constexpr int BB = 8;
constexpr int NPTS = 2048;
constexpr int CC = 128;
constexpr int MM = BB * NPTS;   // 16384
constexpr int OO = 256;
constexpr int K1 = 160;         // 131 padded to multiple of 32
constexpr int KNNK = 16;
constexpr int NQB = 2048;       // knn blocks (8 queries each)

typedef __attribute__((ext_vector_type(8))) short bf16x8;
typedef __attribute__((ext_vector_type(8))) unsigned short u16x8;
typedef __attribute__((ext_vector_type(4))) float f32x4;

__device__ __forceinline__ unsigned short f2bf(float v) {
  unsigned u = __builtin_bit_cast(unsigned, v);
  u += 0x7FFFu + ((u >> 16) & 1u);
  return (unsigned short)(u >> 16);
}

__device__ __forceinline__ float bf2f(unsigned short s) {
  unsigned u = (unsigned)s << 16;
  return __builtin_bit_cast(float, u);
}

__device__ __forceinline__ unsigned long long shflxor64(unsigned long long v, int m) {
  int lo = __shfl_xor((int)(unsigned)v, m, 64);
  int hi = __shfl_xor((int)(unsigned)(v >> 32), m, 64);
  return ((unsigned long long)(unsigned)hi << 32) | (unsigned)lo;
}

// Cheap xor-partner exchange: DPP for xor1/2, ds_swizzle for xor4/8/16, shfl for 32.
template <int J>
__device__ __forceinline__ unsigned long long partner64(unsigned long long v) {
  int lo = (int)(unsigned)v, hi = (int)(unsigned)(v >> 32);
  int plo, phi;
  if constexpr (J == 1) {        // quad_perm [1,0,3,2] = 0xB1
    plo = __builtin_amdgcn_mov_dpp(lo, 0xB1, 0xF, 0xF, true);
    phi = __builtin_amdgcn_mov_dpp(hi, 0xB1, 0xF, 0xF, true);
  } else if constexpr (J == 2) { // quad_perm [2,3,0,1] = 0x4E
    plo = __builtin_amdgcn_mov_dpp(lo, 0x4E, 0xF, 0xF, true);
    phi = __builtin_amdgcn_mov_dpp(hi, 0x4E, 0xF, 0xF, true);
  } else if constexpr (J == 4) {
    plo = __builtin_amdgcn_ds_swizzle(lo, 0x101F);
    phi = __builtin_amdgcn_ds_swizzle(hi, 0x101F);
  } else if constexpr (J == 8) {
    plo = __builtin_amdgcn_ds_swizzle(lo, 0x201F);
    phi = __builtin_amdgcn_ds_swizzle(hi, 0x201F);
  } else if constexpr (J == 16) {
    plo = __builtin_amdgcn_ds_swizzle(lo, 0x401F);
    phi = __builtin_amdgcn_ds_swizzle(hi, 0x401F);
  } else {
    plo = __shfl_xor(lo, 32, 64);
    phi = __shfl_xor(hi, 32, 64);
  }
  return ((unsigned long long)(unsigned)phi << 32) | (unsigned)plo;
}

__device__ __forceinline__ unsigned long long bitonic_sort64(unsigned long long key, int lane) {
#define BSTAGE(K, J)                                                        \
  {                                                                         \
    unsigned long long o = partner64<J>(key);                               \
    bool keepMin = (((lane & (K)) == 0) == ((lane & (J)) == 0));            \
    bool less = key < o;                                                    \
    key = (less == keepMin) ? key : o;                                      \
  }
  BSTAGE(2, 1)
  BSTAGE(4, 2) BSTAGE(4, 1)
  BSTAGE(8, 4) BSTAGE(8, 2) BSTAGE(8, 1)
  BSTAGE(16, 8) BSTAGE(16, 4) BSTAGE(16, 2) BSTAGE(16, 1)
  BSTAGE(32, 16) BSTAGE(32, 8) BSTAGE(32, 4) BSTAGE(32, 2) BSTAGE(32, 1)
  BSTAGE(64, 32) BSTAGE(64, 16) BSTAGE(64, 8) BSTAGE(64, 4) BSTAGE(64, 2) BSTAGE(64, 1)
#undef BSTAGE
  return key;
}

__device__ __forceinline__ unsigned long long u64min(unsigned long long a, unsigned long long b) {
  return a < b ? a : b;
}

// Fused: blocks [0,2048) = exact 16-NN (8 queries/block, 1 wave/query);
// blocks [2048,2256) = weight transpose/cast; block 2256 = stats zero.
// key = (f32_dist_bits << 11) | idx, unique -> (d, idx) lexicographic order
// matches jax.lax.top_k tie rule. VGPR <= 64 (launch_bounds 8 waves/EU) so
// pass 2 RECOMPUTES distances from LDS (bit-identical, contract off).
__global__ __launch_bounds__(512, 8) void knn_prep(const float* __restrict__ pos,
                                                   int* __restrict__ nn_idx,
                                                   const float* __restrict__ W1,
                                                   const float* __restrict__ W2,
                                                   unsigned short* __restrict__ W1T,
                                                   unsigned short* __restrict__ W2T,
                                                   double* __restrict__ stats) {
#pragma clang fp contract(off)
  __shared__ float2 pxy[NPTS];
  __shared__ float pzz[NPTS];
  __shared__ unsigned long long sbuf[8][128];
  const int tid = threadIdx.x;
  if (blockIdx.x >= NQB) {
    const int i2 = blockIdx.x - NQB;
    if (i2 == 208) {
      for (int i = tid; i < 1024; i += 512) stats[i] = 0.0;
      return;
    }
    const int i = i2 * 512 + tid;   // 0 .. 106495 exactly covered by 208 blocks
    if (i < 256 * K1) {
      const int n = i / K1, k = i - n * K1;
      W1T[i] = f2bf(k < 131 ? W1[k * 256 + n] : 0.f);
    } else {
      const int j = i - 256 * K1;
      const int n = j >> 8, k = j & 255;
      W2T[j] = f2bf(W2[k * 256 + n]);
    }
    return;
  }
  const int b = blockIdx.x >> 8;
  const float* pb = pos + (size_t)b * NPTS * 3;
  for (int i = tid; i < NPTS; i += 512) {
    pxy[i] = make_float2(pb[3 * i], pb[3 * i + 1]);
    pzz[i] = pb[3 * i + 2];
  }
  __syncthreads();
  const int lane = tid & 63;
  const int wid = tid >> 6;                        // 0..7
  const int q = ((blockIdx.x & 255) << 3) + wid;   // query within batch
  const float2 qxy = pxy[q];
  const float qz = pzz[q];

  // Pass 1: per-lane min key over candidates j = lane + 64*t
  unsigned long long mink = ~0ull;
  for (int t = 0; t < 32; ++t) {
    const int j = lane + (t << 6);
    float2 pp = pxy[j];
    float dx = qxy.x - pp.x;
    float dy = qxy.y - pp.y;
    float dz = qz - pzz[j];
    float d = ((dx * dx) + (dy * dy)) + (dz * dz);  // reference order, no fma
    unsigned long long key = ((unsigned long long)__float_as_uint(d) << 11) | (unsigned)j;
    mink = u64min(mink, key);
  }
  unsigned long long skey = bitonic_sort64(mink, lane);
  unsigned Tlo = (unsigned)__builtin_amdgcn_readlane((int)(unsigned)skey, 15);
  unsigned Thi = (unsigned)__builtin_amdgcn_readlane((int)(unsigned)(skey >> 32), 15);
  const unsigned long long Tkey = ((unsigned long long)Thi << 32) | Tlo;

  // Pass 2: recompute keys, compact survivors (key <= Tkey) into LDS.
  unsigned long long* buf = sbuf[wid];
  int base = 0;
  for (int t = 0; t < 32; ++t) {
    const int j = lane + (t << 6);
    float2 pp = pxy[j];
    float dx = qxy.x - pp.x;
    float dy = qxy.y - pp.y;
    float dz = qz - pzz[j];
    float d = ((dx * dx) + (dy * dy)) + (dz * dz);
    unsigned long long key = ((unsigned long long)__float_as_uint(d) << 11) | (unsigned)j;
    bool surv = key <= Tkey;
    unsigned long long mask = __ballot(surv);
    if (surv) {
      int off = __popcll(mask & ((1ull << lane) - 1ull));
      if (base + off < 128) buf[base + off] = key;
    }
    base += (int)__popcll(mask);
  }

  int* out = nn_idx + ((size_t)b * NPTS + q) * KNNK;
  if (base <= 64) {
    // common path (P ~ 1): full bitonic sort of survivors
    unsigned long long key = (lane < base) ? buf[lane] : ~0ull;
    key = bitonic_sort64(key, lane);
    if (lane < 16) out[lane] = (int)(key & 2047ull);
  } else if (base <= 128) {
    // rare: 2 keys/lane iterative wave-min extraction (keys unique)
    unsigned long long k0 = buf[lane];
    unsigned long long k1 = (64 + lane < base) ? buf[64 + lane] : ~0ull;
    for (int o = 0; o < 16; ++o) {
      unsigned long long m = u64min(k0, k1);
#pragma unroll
      for (int off = 32; off > 0; off >>= 1) m = u64min(m, shflxor64(m, off));
      if (lane == 0) out[o] = (int)(m & 2047ull);
      if (k0 == m) k0 = ~0ull;
      if (k1 == m) k1 = ~0ull;
    }
  } else {
    // ~never: exact recompute-extraction over all candidates
    unsigned long long prev = 0;
    for (int o = 0; o < 16; ++o) {
      unsigned long long m = ~0ull;
      for (int t = 0; t < 32; ++t) {
        const int j = lane + (t << 6);
        float2 pp = pxy[j];
        float dx = qxy.x - pp.x;
        float dy = qxy.y - pp.y;
        float dz = qz - pzz[j];
        float d = ((dx * dx) + (dy * dy)) + (dz * dz);
        unsigned long long key = ((unsigned long long)__float_as_uint(d) << 11) | (unsigned)j;
        if (o == 0 || key > prev) m = u64min(m, key);
      }
#pragma unroll
      for (int off = 32; off > 0; off >>= 1) m = u64min(m, shflxor64(m, off));
      if (lane == 0) out[o] = (int)(m & 2047ull);
      prev = m;
    }
  }
}

// One wave per point. Lane handles channels (2*lane, 2*lane+1) via float2
// coalesced reads (512B per neighbor row). Same f32 sum order as before.
__global__ __launch_bounds__(256) void gather_avg(const float* __restrict__ x,
                                                  const float* __restrict__ pos,
                                                  const int* __restrict__ nn_idx,
                                                  unsigned short* __restrict__ avg) {
  const int lane = threadIdx.x & 63;
  const int wid = threadIdx.x >> 6;
  const int p = blockIdx.x * 4 + wid;
  const int b = p >> 11;
  const int* ip = nn_idx + (size_t)p * KNNK;
  int idx[16];
#pragma unroll
  for (int k = 0; k < 16; ++k) idx[k] = ip[k];
  const float* xb = x + (size_t)b * NPTS * CC;
  float ax = 0.f, ay = 0.f;
#pragma unroll
  for (int k = 0; k < 16; ++k) {
    float2 v = *(const float2*)(xb + (size_t)idx[k] * CC + lane * 2);
    ax += v.x;
    ay += v.y;
  }
  unsigned short h0 = f2bf(ax * 0.0625f);
  unsigned short h1 = f2bf(ay * 0.0625f);
  *(unsigned*)(avg + (size_t)p * K1 + lane * 2) = (unsigned)h0 | ((unsigned)h1 << 16);
  if (lane < 32) {
    unsigned short o = 0;
    if (lane < 3) {
      const float* pb = pos + (size_t)b * NPTS * 3;
      float v = 0.f;
#pragma unroll
      for (int k = 0; k < 16; ++k) v += pb[idx[k] * 3 + lane];
      o = f2bf(v * 0.0625f);
    }
    avg[(size_t)p * K1 + 128 + lane] = o;
  }
}

// GEMM + bias; per-column sum/sumsq -> global doubles; writes pre-act bf16.
// BN_IN: applies layer-1 BN+ReLU to A elements during LDS staging (values
// bit-identical to the old separate bn_apply pass writing hbuf).
template <bool BN_IN>
__global__ __launch_bounds__(256) void gemm_stats(
    const unsigned short* __restrict__ A, const unsigned short* __restrict__ BT,
    const float* __restrict__ bias,
    const double* __restrict__ dsumIn, const double* __restrict__ dsumsqIn,
    const float* __restrict__ gIn, const float* __restrict__ beIn,
    double* __restrict__ dsum, double* __restrict__ dsumsq,
    unsigned short* __restrict__ pre, int Kp) {
  __shared__ __align__(16) unsigned short As[64][56];
  __shared__ __align__(16) unsigned short Bs[64][56];
  __shared__ float sSum[64], sSq[64];
  __shared__ float sScA[256], sShA[256];
  const int tid = threadIdx.x;
  if (tid < 64) { sSum[tid] = 0.f; sSq[tid] = 0.f; }
  if constexpr (BN_IN) {
    double mu = dsumIn[tid] * (1.0 / 16384.0);
    double var = dsumsqIn[tid] * (1.0 / 16384.0) - mu * mu;
    float sc = (float)((double)gIn[tid] / sqrt(var + 1e-5));
    sScA[tid] = sc;
    sShA[tid] = beIn[tid] - (float)mu * sc;
    __syncthreads();
  }
  const int m0 = blockIdx.x * 64;
  const int n0 = blockIdx.y * 64;
  const int w = tid >> 6, lane = tid & 63;
  const int wr = w >> 1, wc = w & 1;
  const int l15 = lane & 15;
  const int g = lane >> 4;
  const int kk = g * 8;
  f32x4 acc[2][2] = {};
  const int sr = tid >> 2;
  const int sk = (tid & 3) * 8;
  const unsigned short* Aptr = A + (size_t)(m0 + sr) * Kp + sk;
  const unsigned short* Bptr = BT + (size_t)(n0 + sr) * Kp + sk;
  for (int k0 = 0; k0 < Kp; k0 += 32) {
    if constexpr (BN_IN) {
      u16x8 a = *(const u16x8*)(Aptr + k0);
      u16x8 ta;
#pragma unroll
      for (int e = 0; e < 8; ++e) {
        const int col = k0 + sk + e;
        float v = fmaf(bf2f(a[e]), sScA[col], sShA[col]);
        ta[e] = f2bf(fmaxf(v, 0.f));
      }
      *(u16x8*)(&As[sr][sk]) = ta;
    } else {
      *(int4*)(&As[sr][sk]) = *(const int4*)(Aptr + k0);
    }
    *(int4*)(&Bs[sr][sk]) = *(const int4*)(Bptr + k0);
    __syncthreads();
    bf16x8 a0  = *(const bf16x8*)(&As[wr * 32 + l15][kk]);
    bf16x8 a1  = *(const bf16x8*)(&As[wr * 32 + 16 + l15][kk]);
    bf16x8 b0  = *(const bf16x8*)(&Bs[wc * 32 + l15][kk]);
    bf16x8 b1v = *(const bf16x8*)(&Bs[wc * 32 + 16 + l15][kk]);
    acc[0][0] = __builtin_amdgcn_mfma_f32_16x16x32_bf16(a0, b0,  acc[0][0], 0, 0, 0);
    acc[0][1] = __builtin_amdgcn_mfma_f32_16x16x32_bf16(a0, b1v, acc[0][1], 0, 0, 0);
    acc[1][0] = __builtin_amdgcn_mfma_f32_16x16x32_bf16(a1, b0,  acc[1][0], 0, 0, 0);
    acc[1][1] = __builtin_amdgcn_mfma_f32_16x16x32_bf16(a1, b1v, acc[1][1], 0, 0, 0);
    __syncthreads();
  }

  float s[2] = {0.f, 0.f}, q2[2] = {0.f, 0.f};
  unsigned short vb[2][2][4];
#pragma unroll
  for (int fc = 0; fc < 2; ++fc) {
    float bv = bias[n0 + wc * 32 + fc * 16 + l15];
#pragma unroll
    for (int fr = 0; fr < 2; ++fr)
#pragma unroll
      for (int r = 0; r < 4; ++r) {
        float xv = acc[fr][fc][r] + bv;
        unsigned short h = f2bf(xv);
        vb[fr][fc][r] = h;
        float xq = bf2f(h);          // stats from the stored bf16 values
        s[fc] += xq;
        q2[fc] = fmaf(xq, xq, q2[fc]);
      }
  }
#pragma unroll
  for (int fc = 0; fc < 2; ++fc) {
    s[fc] += __shfl_xor(s[fc], 16, 64);
    s[fc] += __shfl_xor(s[fc], 32, 64);
    q2[fc] += __shfl_xor(q2[fc], 16, 64);
    q2[fc] += __shfl_xor(q2[fc], 32, 64);
  }
  if (lane < 16) {
#pragma unroll
    for (int fc = 0; fc < 2; ++fc) {
      atomicAdd(&sSum[wc * 32 + fc * 16 + lane], s[fc]);
      atomicAdd(&sSq[wc * 32 + fc * 16 + lane], q2[fc]);
    }
  }
  // write pre-activation bf16 while the LDS reduction settles
#pragma unroll
  for (int fc = 0; fc < 2; ++fc) {
    int col = n0 + wc * 32 + fc * 16 + l15;
#pragma unroll
    for (int fr = 0; fr < 2; ++fr)
#pragma unroll
      for (int r = 0; r < 4; ++r) {
        int row = m0 + wr * 32 + fr * 16 + g * 4 + r;
        pre[(size_t)row * OO + col] = vb[fr][fc][r];
      }
  }
  __syncthreads();
  if (tid < 64) {
    atomicAdd(&dsum[n0 + tid], (double)sSum[tid]);
    atomicAdd(&dsumsq[n0 + tid], (double)sSq[tid]);
  }
}

// Streams pre (bf16 [MM][256]) -> BN -> f32 out. Each block derives
// scale/shift from the global double stats itself.
__global__ __launch_bounds__(256) void bn_apply(const unsigned short* __restrict__ pre,
                                                const double* __restrict__ dsum,
                                                const double* __restrict__ dsumsq,
                                                const float* __restrict__ gamma,
                                                const float* __restrict__ beta,
                                                float* __restrict__ outp) {
  __shared__ float sSc[256], sSh[256];
  const int tid = threadIdx.x;
  {
    double mu = dsum[tid] * (1.0 / 16384.0);
    double var = dsumsq[tid] * (1.0 / 16384.0) - mu * mu;
    float sc = (float)((double)gamma[tid] / sqrt(var + 1e-5));
    sSc[tid] = sc;
    sSh[tid] = beta[tid] - (float)mu * sc;
  }
  __syncthreads();
  const int cg = (tid & 31) * 8;
  float sc[8], sh[8];
#pragma unroll
  for (int j = 0; j < 8; ++j) { sc[j] = sSc[cg + j]; sh[j] = sSh[cg + j]; }
  const int r0 = blockIdx.x * 32 + (tid >> 5);
#pragma unroll
  for (int it = 0; it < 4; ++it) {
    const int row = r0 + it * 8;
    u16x8 v = *(const u16x8*)(pre + (size_t)row * OO + cg);
    float4 o0, o1;
    o0.x = fmaf(bf2f(v[0]), sc[0], sh[0]);
    o0.y = fmaf(bf2f(v[1]), sc[1], sh[1]);
    o0.z = fmaf(bf2f(v[2]), sc[2], sh[2]);
    o0.w = fmaf(bf2f(v[3]), sc[3], sh[3]);
    o1.x = fmaf(bf2f(v[4]), sc[4], sh[4]);
    o1.y = fmaf(bf2f(v[5]), sc[5], sh[5]);
    o1.z = fmaf(bf2f(v[6]), sc[6], sh[6]);
    o1.w = fmaf(bf2f(v[7]), sc[7], sh[7]);
    float* op = outp + (size_t)row * OO + cg;
    *(float4*)op = o0;
    *(float4*)(op + 4) = o1;
  }
}

}  // namespace

extern "C" void kernel_launch(void* const* d_in, const int* in_sizes, int n_in,
                              void* d_out, int out_size, void* d_ws, size_t ws_size,
                              hipStream_t stream) {
  const float* x   = (const float*)d_in[0];
  const float* pos = (const float*)d_in[1];
  const float* W1  = (const float*)d_in[2];
  const float* b1  = (const float*)d_in[3];
  const float* g1  = (const float*)d_in[4];
  const float* be1 = (const float*)d_in[5];
  const float* W2  = (const float*)d_in[6];
  const float* b2  = (const float*)d_in[7];
  const float* g2  = (const float*)d_in[8];
  const float* be2 = (const float*)d_in[9];

  char* ws = (char*)d_ws;
  double* stats        = (double*)(ws + 0);                  // 1024 doubles
  int* nn_idx          = (int*)(ws + 12288);                 // 16384*16 int
  unsigned short* avg  = (unsigned short*)(ws + 1060864);    // 16384*160 bf16
  unsigned short* W1T  = (unsigned short*)(ws + 6303744);    // 256*160 bf16
  unsigned short* W2T  = (unsigned short*)(ws + 6385664);    // 256*256 bf16
  unsigned short* pre1 = (unsigned short*)(ws + 6516736);    // 16384*256 bf16
  unsigned short* pre2 = (unsigned short*)(ws + 14905344);   // 16384*256 bf16

  knn_prep<<<NQB + 209, 512, 0, stream>>>(pos, nn_idx, W1, W2, W1T, W2T, stats);
  gather_avg<<<MM / 4, 256, 0, stream>>>(x, pos, nn_idx, avg);
  gemm_stats<false><<<dim3(MM / 64, OO / 64), 256, 0, stream>>>(
      avg, W1T, b1, nullptr, nullptr, nullptr, nullptr,
      stats, stats + 256, pre1, K1);
  gemm_stats<true><<<dim3(MM / 64, OO / 64), 256, 0, stream>>>(
      pre1, W2T, b2, stats, stats + 256, g1, be1,
      stats + 512, stats + 768, pre2, OO);
  bn_apply<<<MM / 32, 256, 0, stream>>>(pre2, stats + 512, stats + 768, g2, be2, (float*)d_out);
}

// Round 7
// 84.461 us; speedup vs baseline: 1.9225x; 1.9225x over previous
//
#include <hip/hip_runtime.h>
#include <hip/hip_bf16.h>

namespace {

constexpr int BB = 8;
constexpr int NPTS = 2048;
constexpr int CC = 128;
constexpr int MM = BB * NPTS;   // 16384
constexpr int OO = 256;
constexpr int K1 = 160;         // 131 padded to multiple of 32
constexpr int KNNK = 16;

typedef __attribute__((ext_vector_type(8))) short bf16x8;
typedef __attribute__((ext_vector_type(8))) unsigned short u16x8;
typedef __attribute__((ext_vector_type(4))) float f32x4;

__device__ __forceinline__ unsigned short f2bf(float v) {
  unsigned u = __builtin_bit_cast(unsigned, v);
  u += 0x7FFFu + ((u >> 16) & 1u);
  return (unsigned short)(u >> 16);
}

__device__ __forceinline__ float bf2f(unsigned short s) {
  unsigned u = (unsigned)s << 16;
  return __builtin_bit_cast(float, u);
}

__device__ __forceinline__ unsigned long long shflxor64(unsigned long long v, int m) {
  int lo = __shfl_xor((int)(unsigned)v, m, 64);
  int hi = __shfl_xor((int)(unsigned)(v >> 32), m, 64);
  return ((unsigned long long)(unsigned)hi << 32) | (unsigned)lo;
}

// Cheap xor-partner exchange: DPP for xor1/2, ds_swizzle for xor4/8/16, shfl for 32.
template <int J>
__device__ __forceinline__ unsigned long long partner64(unsigned long long v) {
  int lo = (int)(unsigned)v, hi = (int)(unsigned)(v >> 32);
  int plo, phi;
  if constexpr (J == 1) {        // quad_perm [1,0,3,2] = 0xB1
    plo = __builtin_amdgcn_mov_dpp(lo, 0xB1, 0xF, 0xF, true);
    phi = __builtin_amdgcn_mov_dpp(hi, 0xB1, 0xF, 0xF, true);
  } else if constexpr (J == 2) { // quad_perm [2,3,0,1] = 0x4E
    plo = __builtin_amdgcn_mov_dpp(lo, 0x4E, 0xF, 0xF, true);
    phi = __builtin_amdgcn_mov_dpp(hi, 0x4E, 0xF, 0xF, true);
  } else if constexpr (J == 4) {
    plo = __builtin_amdgcn_ds_swizzle(lo, 0x101F);
    phi = __builtin_amdgcn_ds_swizzle(hi, 0x101F);
  } else if constexpr (J == 8) {
    plo = __builtin_amdgcn_ds_swizzle(lo, 0x201F);
    phi = __builtin_amdgcn_ds_swizzle(hi, 0x201F);
  } else if constexpr (J == 16) {
    plo = __builtin_amdgcn_ds_swizzle(lo, 0x401F);
    phi = __builtin_amdgcn_ds_swizzle(hi, 0x401F);
  } else {
    plo = __shfl_xor(lo, 32, 64);
    phi = __shfl_xor(hi, 32, 64);
  }
  return ((unsigned long long)(unsigned)phi << 32) | (unsigned)plo;
}

__device__ __forceinline__ unsigned long long bitonic_sort64(unsigned long long key, int lane) {
#define BSTAGE(K, J)                                                        \
  {                                                                         \
    unsigned long long o = partner64<J>(key);                               \
    bool keepMin = (((lane & (K)) == 0) == ((lane & (J)) == 0));            \
    bool less = key < o;                                                    \
    key = (less == keepMin) ? key : o;                                      \
  }
  BSTAGE(2, 1)
  BSTAGE(4, 2) BSTAGE(4, 1)
  BSTAGE(8, 4) BSTAGE(8, 2) BSTAGE(8, 1)
  BSTAGE(16, 8) BSTAGE(16, 4) BSTAGE(16, 2) BSTAGE(16, 1)
  BSTAGE(32, 16) BSTAGE(32, 8) BSTAGE(32, 4) BSTAGE(32, 2) BSTAGE(32, 1)
  BSTAGE(64, 32) BSTAGE(64, 16) BSTAGE(64, 8) BSTAGE(64, 4) BSTAGE(64, 2) BSTAGE(64, 1)
#undef BSTAGE
  return key;
}

__device__ __forceinline__ unsigned long long u64min(unsigned long long a, unsigned long long b) {
  return a < b ? a : b;
}

// Exact 16-NN, one wave per query, 4 queries/block. key = (f32_dist_bits<<11)|idx
// (unique -> (d,idx) lexicographic == jax.lax.top_k tie rule). Pass 1 caches the
// 32 per-lane DISTANCES in registers (f32, not u64 pairs -> ~55 VGPR, no spill
// at the (256,6) budget of 85). Pass 2 rebuilds keys from regs and compacts
// survivors (<= Tkey) into a 64-slot LDS buffer; overflow (P~0) falls back to
// buffer-free extraction. LDS = 16K+8K+2K = 26624 B -> 6 blocks/CU, 24 waves.
__global__ __launch_bounds__(256, 6) void knn_kernel(const float* __restrict__ pos,
                                                     int* __restrict__ nn_idx) {
#pragma clang fp contract(off)
  __shared__ float2 pxy[NPTS];
  __shared__ float pzz[NPTS];
  __shared__ unsigned long long sbuf[4][64];
  const int b = blockIdx.y;
  const int tid = threadIdx.x;
  const float* pb = pos + (size_t)b * NPTS * 3;
  for (int i = tid; i < NPTS; i += 256) {
    pxy[i] = make_float2(pb[3 * i], pb[3 * i + 1]);
    pzz[i] = pb[3 * i + 2];
  }
  __syncthreads();
  const int lane = tid & 63;
  const int wid = tid >> 6;
  const int q = blockIdx.x * 4 + wid;  // query within batch
  const float2 qxy = pxy[q];
  const float qz = pzz[q];

  float dvals[32];
  unsigned long long mink = ~0ull;
#pragma unroll
  for (int t = 0; t < 32; ++t) {
    const int j = lane + (t << 6);
    float2 pp = pxy[j];
    float dx = qxy.x - pp.x;
    float dy = qxy.y - pp.y;
    float dz = qz - pzz[j];
    float d = ((dx * dx) + (dy * dy)) + (dz * dz);  // reference order, no fma
    dvals[t] = d;
    unsigned long long key = ((unsigned long long)__float_as_uint(d) << 11) | (unsigned)j;
    mink = u64min(mink, key);
  }
  unsigned long long skey = bitonic_sort64(mink, lane);
  unsigned Tlo = (unsigned)__builtin_amdgcn_readlane((int)(unsigned)skey, 15);
  unsigned Thi = (unsigned)__builtin_amdgcn_readlane((int)(unsigned)(skey >> 32), 15);
  const unsigned long long Tkey = ((unsigned long long)Thi << 32) | Tlo;

  // Pass 2: rebuild keys from cached distances, compact survivors into LDS.
  unsigned long long* buf = sbuf[wid];
  int base = 0;
#pragma unroll
  for (int t = 0; t < 32; ++t) {
    unsigned long long key =
        ((unsigned long long)__float_as_uint(dvals[t]) << 11) | (unsigned)(lane + (t << 6));
    bool surv = key <= Tkey;
    unsigned long long mask = __ballot(surv);
    if (surv) {
      int off = __popcll(mask & ((1ull << lane) - 1ull));
      if (base + off < 64) buf[base + off] = key;
    }
    base += (int)__popcll(mask);
  }

  int* out = nn_idx + ((size_t)b * NPTS + q) * KNNK;
  if (base <= 64) {
    // common path (P ~ 1): full bitonic sort of survivors
    unsigned long long key = (lane < base) ? buf[lane] : ~0ull;
    key = bitonic_sort64(key, lane);
    if (lane < 16) out[lane] = (int)(key & 2047ull);
  } else {
    // ~never: exact extraction from cached distances, no buffer needed
    unsigned long long prev = 0;
    for (int o = 0; o < 16; ++o) {
      unsigned long long m = ~0ull;
#pragma unroll
      for (int t = 0; t < 32; ++t) {
        unsigned long long key =
            ((unsigned long long)__float_as_uint(dvals[t]) << 11) | (unsigned)(lane + (t << 6));
        if (o == 0 || key > prev) m = u64min(m, key);
      }
#pragma unroll
      for (int off = 32; off > 0; off >>= 1) m = u64min(m, shflxor64(m, off));
      if (lane == 0) out[o] = (int)(m & 2047ull);
      prev = m;
    }
  }
}

// Blocks [0,4096): one wave per point, gather+average (channels via float2).
// Blocks [4096,4304): weight transpose/cast. Block 4304: zero stats.
__global__ __launch_bounds__(256) void gather_prep(const float* __restrict__ x,
                                                   const float* __restrict__ pos,
                                                   const int* __restrict__ nn_idx,
                                                   unsigned short* __restrict__ avg,
                                                   const float* __restrict__ W1,
                                                   const float* __restrict__ W2,
                                                   unsigned short* __restrict__ W1T,
                                                   unsigned short* __restrict__ W2T,
                                                   double* __restrict__ stats) {
  const int tid = threadIdx.x;
  if (blockIdx.x >= MM / 4) {
    const int i2 = blockIdx.x - MM / 4;
    if (i2 == 208) {
      for (int i = tid; i < 1024; i += 256) stats[i] = 0.0;
      return;
    }
    const int i = i2 * 512 + (tid << 1);   // 2 elems/thread: 208 blocks cover 106496
#pragma unroll
    for (int e = 0; e < 2; ++e) {
      const int ii = i + e;
      if (ii < 256 * K1) {
        const int n = ii / K1, k = ii - n * K1;
        W1T[ii] = f2bf(k < 131 ? W1[k * 256 + n] : 0.f);
      } else {
        const int j = ii - 256 * K1;
        const int n = j >> 8, k = j & 255;
        W2T[j] = f2bf(W2[k * 256 + n]);
      }
    }
    return;
  }
  const int lane = tid & 63;
  const int wid = tid >> 6;
  const int p = blockIdx.x * 4 + wid;
  const int b = p >> 11;
  const int* ip = nn_idx + (size_t)p * KNNK;
  int idx[16];
#pragma unroll
  for (int k = 0; k < 16; ++k) idx[k] = ip[k];
  const float* xb = x + (size_t)b * NPTS * CC;
  float ax = 0.f, ay = 0.f;
#pragma unroll
  for (int k = 0; k < 16; ++k) {
    float2 v = *(const float2*)(xb + (size_t)idx[k] * CC + lane * 2);
    ax += v.x;
    ay += v.y;
  }
  unsigned short h0 = f2bf(ax * 0.0625f);
  unsigned short h1 = f2bf(ay * 0.0625f);
  *(unsigned*)(avg + (size_t)p * K1 + lane * 2) = (unsigned)h0 | ((unsigned)h1 << 16);
  if (lane < 32) {
    unsigned short o = 0;
    if (lane < 3) {
      const float* pb = pos + (size_t)b * NPTS * 3;
      float v = 0.f;
#pragma unroll
      for (int k = 0; k < 16; ++k) v += pb[idx[k] * 3 + lane];
      o = f2bf(v * 0.0625f);
    }
    avg[(size_t)p * K1 + 128 + lane] = o;
  }
}

// GEMM + bias; per-column sum/sumsq -> global doubles; writes pre-act bf16.
// BN_IN: applies layer-1 BN+ReLU to A elements during LDS staging (values
// bit-identical to a separate bn_apply pass).
template <bool BN_IN>
__global__ __launch_bounds__(256) void gemm_stats(
    const unsigned short* __restrict__ A, const unsigned short* __restrict__ BT,
    const float* __restrict__ bias,
    const double* __restrict__ dsumIn, const double* __restrict__ dsumsqIn,
    const float* __restrict__ gIn, const float* __restrict__ beIn,
    double* __restrict__ dsum, double* __restrict__ dsumsq,
    unsigned short* __restrict__ pre, int Kp) {
  __shared__ __align__(16) unsigned short As[64][56];
  __shared__ __align__(16) unsigned short Bs[64][56];
  __shared__ float sSum[64], sSq[64];
  __shared__ float sScA[256], sShA[256];
  const int tid = threadIdx.x;
  if (tid < 64) { sSum[tid] = 0.f; sSq[tid] = 0.f; }
  if constexpr (BN_IN) {
    double mu = dsumIn[tid] * (1.0 / 16384.0);
    double var = dsumsqIn[tid] * (1.0 / 16384.0) - mu * mu;
    float sc = (float)((double)gIn[tid] / sqrt(var + 1e-5));
    sScA[tid] = sc;
    sShA[tid] = beIn[tid] - (float)mu * sc;
    __syncthreads();
  }
  const int m0 = blockIdx.x * 64;
  const int n0 = blockIdx.y * 64;
  const int w = tid >> 6, lane = tid & 63;
  const int wr = w >> 1, wc = w & 1;
  const int l15 = lane & 15;
  const int g = lane >> 4;
  const int kk = g * 8;
  f32x4 acc[2][2] = {};
  const int sr = tid >> 2;
  const int sk = (tid & 3) * 8;
  const unsigned short* Aptr = A + (size_t)(m0 + sr) * Kp + sk;
  const unsigned short* Bptr = BT + (size_t)(n0 + sr) * Kp + sk;
  for (int k0 = 0; k0 < Kp; k0 += 32) {
    if constexpr (BN_IN) {
      u16x8 a = *(const u16x8*)(Aptr + k0);
      u16x8 ta;
#pragma unroll
      for (int e = 0; e < 8; ++e) {
        const int col = k0 + sk + e;
        float v = fmaf(bf2f(a[e]), sScA[col], sShA[col]);
        ta[e] = f2bf(fmaxf(v, 0.f));
      }
      *(u16x8*)(&As[sr][sk]) = ta;
    } else {
      *(int4*)(&As[sr][sk]) = *(const int4*)(Aptr + k0);
    }
    *(int4*)(&Bs[sr][sk]) = *(const int4*)(Bptr + k0);
    __syncthreads();
    bf16x8 a0  = *(const bf16x8*)(&As[wr * 32 + l15][kk]);
    bf16x8 a1  = *(const bf16x8*)(&As[wr * 32 + 16 + l15][kk]);
    bf16x8 b0  = *(const bf16x8*)(&Bs[wc * 32 + l15][kk]);
    bf16x8 b1v = *(const bf16x8*)(&Bs[wc * 32 + 16 + l15][kk]);
    acc[0][0] = __builtin_amdgcn_mfma_f32_16x16x32_bf16(a0, b0,  acc[0][0], 0, 0, 0);
    acc[0][1] = __builtin_amdgcn_mfma_f32_16x16x32_bf16(a0, b1v, acc[0][1], 0, 0, 0);
    acc[1][0] = __builtin_amdgcn_mfma_f32_16x16x32_bf16(a1, b0,  acc[1][0], 0, 0, 0);
    acc[1][1] = __builtin_amdgcn_mfma_f32_16x16x32_bf16(a1, b1v, acc[1][1], 0, 0, 0);
    __syncthreads();
  }

  float s[2] = {0.f, 0.f}, q2[2] = {0.f, 0.f};
  unsigned short vb[2][2][4];
#pragma unroll
  for (int fc = 0; fc < 2; ++fc) {
    float bv = bias[n0 + wc * 32 + fc * 16 + l15];
#pragma unroll
    for (int fr = 0; fr < 2; ++fr)
#pragma unroll
      for (int r = 0; r < 4; ++r) {
        float xv = acc[fr][fc][r] + bv;
        unsigned short h = f2bf(xv);
        vb[fr][fc][r] = h;
        float xq = bf2f(h);          // stats from the stored bf16 values
        s[fc] += xq;
        q2[fc] = fmaf(xq, xq, q2[fc]);
      }
  }
#pragma unroll
  for (int fc = 0; fc < 2; ++fc) {
    s[fc] += __shfl_xor(s[fc], 16, 64);
    s[fc] += __shfl_xor(s[fc], 32, 64);
    q2[fc] += __shfl_xor(q2[fc], 16, 64);
    q2[fc] += __shfl_xor(q2[fc], 32, 64);
  }
  if (lane < 16) {
#pragma unroll
    for (int fc = 0; fc < 2; ++fc) {
      atomicAdd(&sSum[wc * 32 + fc * 16 + lane], s[fc]);
      atomicAdd(&sSq[wc * 32 + fc * 16 + lane], q2[fc]);
    }
  }
  // write pre-activation bf16 while the LDS reduction settles
#pragma unroll
  for (int fc = 0; fc < 2; ++fc) {
    int col = n0 + wc * 32 + fc * 16 + l15;
#pragma unroll
    for (int fr = 0; fr < 2; ++fr)
#pragma unroll
      for (int r = 0; r < 4; ++r) {
        int row = m0 + wr * 32 + fr * 16 + g * 4 + r;
        pre[(size_t)row * OO + col] = vb[fr][fc][r];
      }
  }
  __syncthreads();
  if (tid < 64) {
    atomicAdd(&dsum[n0 + tid], (double)sSum[tid]);
    atomicAdd(&dsumsq[n0 + tid], (double)sSq[tid]);
  }
}

// Streams pre (bf16 [MM][256]) -> BN -> f32 out. Each block derives
// scale/shift from the global double stats itself.
__global__ __launch_bounds__(256) void bn_apply(const unsigned short* __restrict__ pre,
                                                const double* __restrict__ dsum,
                                                const double* __restrict__ dsumsq,
                                                const float* __restrict__ gamma,
                                                const float* __restrict__ beta,
                                                float* __restrict__ outp) {
  __shared__ float sSc[256], sSh[256];
  const int tid = threadIdx.x;
  {
    double mu = dsum[tid] * (1.0 / 16384.0);
    double var = dsumsq[tid] * (1.0 / 16384.0) - mu * mu;
    float sc = (float)((double)gamma[tid] / sqrt(var + 1e-5));
    sSc[tid] = sc;
    sSh[tid] = beta[tid] - (float)mu * sc;
  }
  __syncthreads();
  const int cg = (tid & 31) * 8;
  float sc[8], sh[8];
#pragma unroll
  for (int j = 0; j < 8; ++j) { sc[j] = sSc[cg + j]; sh[j] = sSh[cg + j]; }
  const int r0 = blockIdx.x * 32 + (tid >> 5);
#pragma unroll
  for (int it = 0; it < 4; ++it) {
    const int row = r0 + it * 8;
    u16x8 v = *(const u16x8*)(pre + (size_t)row * OO + cg);
    float4 o0, o1;
    o0.x = fmaf(bf2f(v[0]), sc[0], sh[0]);
    o0.y = fmaf(bf2f(v[1]), sc[1], sh[1]);
    o0.z = fmaf(bf2f(v[2]), sc[2], sh[2]);
    o0.w = fmaf(bf2f(v[3]), sc[3], sh[3]);
    o1.x = fmaf(bf2f(v[4]), sc[4], sh[4]);
    o1.y = fmaf(bf2f(v[5]), sc[5], sh[5]);
    o1.z = fmaf(bf2f(v[6]), sc[6], sh[6]);
    o1.w = fmaf(bf2f(v[7]), sc[7], sh[7]);
    float* op = outp + (size_t)row * OO + cg;
    *(float4*)op = o0;
    *(float4*)(op + 4) = o1;
  }
}

}  // namespace

extern "C" void kernel_launch(void* const* d_in, const int* in_sizes, int n_in,
                              void* d_out, int out_size, void* d_ws, size_t ws_size,
                              hipStream_t stream) {
  const float* x   = (const float*)d_in[0];
  const float* pos = (const float*)d_in[1];
  const float* W1  = (const float*)d_in[2];
  const float* b1  = (const float*)d_in[3];
  const float* g1  = (const float*)d_in[4];
  const float* be1 = (const float*)d_in[5];
  const float* W2  = (const float*)d_in[6];
  const float* b2  = (const float*)d_in[7];
  const float* g2  = (const float*)d_in[8];
  const float* be2 = (const float*)d_in[9];

  char* ws = (char*)d_ws;
  double* stats        = (double*)(ws + 0);                  // 1024 doubles
  int* nn_idx          = (int*)(ws + 12288);                 // 16384*16 int
  unsigned short* avg  = (unsigned short*)(ws + 1060864);    // 16384*160 bf16
  unsigned short* W1T  = (unsigned short*)(ws + 6303744);    // 256*160 bf16
  unsigned short* W2T  = (unsigned short*)(ws + 6385664);    // 256*256 bf16
  unsigned short* pre1 = (unsigned short*)(ws + 6516736);    // 16384*256 bf16
  unsigned short* pre2 = (unsigned short*)(ws + 14905344);   // 16384*256 bf16

  knn_kernel<<<dim3(NPTS / 4, BB), 256, 0, stream>>>(pos, nn_idx);
  gather_prep<<<MM / 4 + 209, 256, 0, stream>>>(x, pos, nn_idx, avg, W1, W2, W1T, W2T, stats);
  gemm_stats<false><<<dim3(MM / 64, OO / 64), 256, 0, stream>>>(
      avg, W1T, b1, nullptr, nullptr, nullptr, nullptr,
      stats, stats + 256, pre1, K1);
  gemm_stats<true><<<dim3(MM / 64, OO / 64), 256, 0, stream>>>(
      pre1, W2T, b2, stats, stats + 256, g1, be1,
      stats + 512, stats + 768, pre2, OO);
  bn_apply<<<MM / 32, 256, 0, stream>>>(pre2, stats + 512, stats + 768, g2, be2, (float*)d_out);
}

// Round 8
// 83.685 us; speedup vs baseline: 1.9403x; 1.0093x over previous
//
#include <hip/hip_runtime.h>
#include <hip/hip_bf16.h>

namespace {

constexpr int BB = 8;
constexpr int NPTS = 2048;
constexpr int CC = 128;
constexpr int MM = BB * NPTS;   // 16384
constexpr int OO = 256;
constexpr int K1 = 160;         // 131 padded to multiple of 32
constexpr int NKNN = MM / 4;    // 4096 knn blocks (4 queries each)

typedef __attribute__((ext_vector_type(8))) short bf16x8;
typedef __attribute__((ext_vector_type(8))) unsigned short u16x8;
typedef __attribute__((ext_vector_type(4))) float f32x4;

__device__ __forceinline__ unsigned short f2bf(float v) {
  unsigned u = __builtin_bit_cast(unsigned, v);
  u += 0x7FFFu + ((u >> 16) & 1u);
  return (unsigned short)(u >> 16);
}

__device__ __forceinline__ float bf2f(unsigned short s) {
  unsigned u = (unsigned)s << 16;
  return __builtin_bit_cast(float, u);
}

__device__ __forceinline__ unsigned long long shflxor64(unsigned long long v, int m) {
  int lo = __shfl_xor((int)(unsigned)v, m, 64);
  int hi = __shfl_xor((int)(unsigned)(v >> 32), m, 64);
  return ((unsigned long long)(unsigned)hi << 32) | (unsigned)lo;
}

// Cheap xor-partner exchange: DPP for xor1/2, ds_swizzle for xor4/8/16, shfl for 32.
template <int J>
__device__ __forceinline__ unsigned long long partner64(unsigned long long v) {
  int lo = (int)(unsigned)v, hi = (int)(unsigned)(v >> 32);
  int plo, phi;
  if constexpr (J == 1) {        // quad_perm [1,0,3,2] = 0xB1
    plo = __builtin_amdgcn_mov_dpp(lo, 0xB1, 0xF, 0xF, true);
    phi = __builtin_amdgcn_mov_dpp(hi, 0xB1, 0xF, 0xF, true);
  } else if constexpr (J == 2) { // quad_perm [2,3,0,1] = 0x4E
    plo = __builtin_amdgcn_mov_dpp(lo, 0x4E, 0xF, 0xF, true);
    phi = __builtin_amdgcn_mov_dpp(hi, 0x4E, 0xF, 0xF, true);
  } else if constexpr (J == 4) {
    plo = __builtin_amdgcn_ds_swizzle(lo, 0x101F);
    phi = __builtin_amdgcn_ds_swizzle(hi, 0x101F);
  } else if constexpr (J == 8) {
    plo = __builtin_amdgcn_ds_swizzle(lo, 0x201F);
    phi = __builtin_amdgcn_ds_swizzle(hi, 0x201F);
  } else if constexpr (J == 16) {
    plo = __builtin_amdgcn_ds_swizzle(lo, 0x401F);
    phi = __builtin_amdgcn_ds_swizzle(hi, 0x401F);
  } else {
    plo = __shfl_xor(lo, 32, 64);
    phi = __shfl_xor(hi, 32, 64);
  }
  return ((unsigned long long)(unsigned)phi << 32) | (unsigned)plo;
}

__device__ __forceinline__ unsigned long long bitonic_sort64(unsigned long long key, int lane) {
#define BSTAGE(K, J)                                                        \
  {                                                                         \
    unsigned long long o = partner64<J>(key);                               \
    bool keepMin = (((lane & (K)) == 0) == ((lane & (J)) == 0));            \
    bool less = key < o;                                                    \
    key = (less == keepMin) ? key : o;                                      \
  }
  BSTAGE(2, 1)
  BSTAGE(4, 2) BSTAGE(4, 1)
  BSTAGE(8, 4) BSTAGE(8, 2) BSTAGE(8, 1)
  BSTAGE(16, 8) BSTAGE(16, 4) BSTAGE(16, 2) BSTAGE(16, 1)
  BSTAGE(32, 16) BSTAGE(32, 8) BSTAGE(32, 4) BSTAGE(32, 2) BSTAGE(32, 1)
  BSTAGE(64, 32) BSTAGE(64, 16) BSTAGE(64, 8) BSTAGE(64, 4) BSTAGE(64, 2) BSTAGE(64, 1)
#undef BSTAGE
  return key;
}

__device__ __forceinline__ unsigned long long u64min(unsigned long long a, unsigned long long b) {
  return a < b ? a : b;
}

// Blocks [0,4096): exact 16-NN (1 wave/query, 4 queries/block) FUSED with the
// neighbor gather+average (indices stay in registers; nn_idx never hits HBM).
// Blocks [4096,4304): weight transpose/cast. Block 4304: stats zero.
// key = (f32_dist_bits<<11)|idx, unique -> (d,idx) lexicographic == top_k ties.
// xy staged in LDS (b64 reads); z read from GLOBAL (pos fits 32KB L1, vmem pipe
// otherwise idle) -> LDS-pipe ops/wave cut ~40%. Gather traffic (L2-heavy)
// overlaps the LDS/VALU-bound KNN phases of co-resident waves.
__global__ __launch_bounds__(256, 6) void knn_gather(const float* __restrict__ pos,
                                                     const float* __restrict__ x,
                                                     unsigned short* __restrict__ avg,
                                                     const float* __restrict__ W1,
                                                     const float* __restrict__ W2,
                                                     unsigned short* __restrict__ W1T,
                                                     unsigned short* __restrict__ W2T,
                                                     double* __restrict__ stats) {
#pragma clang fp contract(off)
  __shared__ float2 pxy[NPTS];
  __shared__ unsigned long long sbuf[4][64];
  const int tid = threadIdx.x;
  if (blockIdx.x >= NKNN) {
    const int i2 = blockIdx.x - NKNN;
    if (i2 == 208) {
      for (int i = tid; i < 1024; i += 256) stats[i] = 0.0;
      return;
    }
    const int i = i2 * 512 + (tid << 1);   // 208 blocks x 512 cover 106496
#pragma unroll
    for (int e = 0; e < 2; ++e) {
      const int ii = i + e;
      if (ii < 256 * K1) {
        const int n = ii / K1, k = ii - n * K1;
        W1T[ii] = f2bf(k < 131 ? W1[k * 256 + n] : 0.f);
      } else {
        const int j = ii - 256 * K1;
        const int n = j >> 8, k = j & 255;
        W2T[j] = f2bf(W2[k * 256 + n]);
      }
    }
    return;
  }
  const int b = blockIdx.x >> 9;           // 512 blocks per batch
  const float* pb = pos + (size_t)b * NPTS * 3;
  for (int i = tid; i < NPTS; i += 256) {
    pxy[i] = make_float2(pb[3 * i], pb[3 * i + 1]);
  }
  __syncthreads();
  const int lane = tid & 63;
  const int wid = tid >> 6;
  const int q = ((blockIdx.x & 511) << 2) + wid;  // query within batch
  const float2 qxy = pxy[q];
  const float qz = pb[3 * q + 2];

  float dvals[32];
  unsigned long long mink = ~0ull;
#pragma unroll
  for (int t = 0; t < 32; ++t) {
    const int j = lane + (t << 6);
    float2 pp = pxy[j];
    float pz = pb[3 * j + 2];              // global: L1-resident, vmem pipe
    float dx = qxy.x - pp.x;
    float dy = qxy.y - pp.y;
    float dz = qz - pz;
    float d = ((dx * dx) + (dy * dy)) + (dz * dz);  // reference order, no fma
    dvals[t] = d;
    unsigned long long key = ((unsigned long long)__float_as_uint(d) << 11) | (unsigned)j;
    mink = u64min(mink, key);
  }
  unsigned long long skey = bitonic_sort64(mink, lane);
  unsigned Tlo = (unsigned)__builtin_amdgcn_readlane((int)(unsigned)skey, 15);
  unsigned Thi = (unsigned)__builtin_amdgcn_readlane((int)(unsigned)(skey >> 32), 15);
  const unsigned long long Tkey = ((unsigned long long)Thi << 32) | Tlo;

  // Pass 2: rebuild keys from cached distances, compact survivors into LDS.
  unsigned long long* buf = sbuf[wid];
  int base = 0;
#pragma unroll
  for (int t = 0; t < 32; ++t) {
    unsigned long long key =
        ((unsigned long long)__float_as_uint(dvals[t]) << 11) | (unsigned)(lane + (t << 6));
    bool surv = key <= Tkey;
    unsigned long long mask = __ballot(surv);
    if (surv) {
      int off = __popcll(mask & ((1ull << lane) - 1ull));
      if (base + off < 64) buf[base + off] = key;
    }
    base += (int)__popcll(mask);
  }

  int myidx = 0;   // lane k (k<16) holds the k-th neighbor index
  if (base <= 64) {
    // common path (P ~ 1): full bitonic sort of survivors
    unsigned long long key = (lane < base) ? buf[lane] : ~0ull;
    key = bitonic_sort64(key, lane);
    if (lane < 16) myidx = (int)(key & 2047ull);
  } else {
    // ~never: exact extraction from cached distances, no buffer needed
    unsigned long long prev = 0;
    for (int o = 0; o < 16; ++o) {
      unsigned long long m = ~0ull;
#pragma unroll
      for (int t = 0; t < 32; ++t) {
        unsigned long long key =
            ((unsigned long long)__float_as_uint(dvals[t]) << 11) | (unsigned)(lane + (t << 6));
        if (o == 0 || key > prev) m = u64min(m, key);
      }
#pragma unroll
      for (int off = 32; off > 0; off >>= 1) m = u64min(m, shflxor64(m, off));
      if (lane == o) myidx = (int)(m & 2047ull);
      prev = m;
    }
  }

  // ---- fused gather+average (indices broadcast via readlane, SALU-cheap) ----
  const float* xb = x + (size_t)b * NPTS * CC;
  float ax = 0.f, ay = 0.f;
  int idxs[16];
#pragma unroll
  for (int k = 0; k < 16; ++k) {
    idxs[k] = __builtin_amdgcn_readlane(myidx, k);
    float2 v = *(const float2*)(xb + (size_t)idxs[k] * CC + lane * 2);
    ax += v.x;
    ay += v.y;
  }
  const size_t p = (size_t)b * NPTS + q;
  unsigned short h0 = f2bf(ax * 0.0625f);
  unsigned short h1 = f2bf(ay * 0.0625f);
  *(unsigned*)(avg + p * K1 + lane * 2) = (unsigned)h0 | ((unsigned)h1 << 16);
  if (lane < 32) {
    unsigned short o = 0;
    if (lane < 3) {
      float v = 0.f;
#pragma unroll
      for (int k = 0; k < 16; ++k) v += pb[idxs[k] * 3 + lane];
      o = f2bf(v * 0.0625f);
    }
    avg[p * K1 + 128 + lane] = o;
  }
}

// GEMM + bias; per-column sum/sumsq -> global doubles; writes pre-act bf16.
// BN_IN: applies layer-1 BN+ReLU to A elements during LDS staging (values
// bit-identical to a separate bn_apply pass).
template <bool BN_IN>
__global__ __launch_bounds__(256) void gemm_stats(
    const unsigned short* __restrict__ A, const unsigned short* __restrict__ BT,
    const float* __restrict__ bias,
    const double* __restrict__ dsumIn, const double* __restrict__ dsumsqIn,
    const float* __restrict__ gIn, const float* __restrict__ beIn,
    double* __restrict__ dsum, double* __restrict__ dsumsq,
    unsigned short* __restrict__ pre, int Kp) {
  __shared__ __align__(16) unsigned short As[64][56];
  __shared__ __align__(16) unsigned short Bs[64][56];
  __shared__ float sSum[64], sSq[64];
  __shared__ float sScA[256], sShA[256];
  const int tid = threadIdx.x;
  if (tid < 64) { sSum[tid] = 0.f; sSq[tid] = 0.f; }
  if constexpr (BN_IN) {
    double mu = dsumIn[tid] * (1.0 / 16384.0);
    double var = dsumsqIn[tid] * (1.0 / 16384.0) - mu * mu;
    float sc = (float)((double)gIn[tid] / sqrt(var + 1e-5));
    sScA[tid] = sc;
    sShA[tid] = beIn[tid] - (float)mu * sc;
    __syncthreads();
  }
  const int m0 = blockIdx.x * 64;
  const int n0 = blockIdx.y * 64;
  const int w = tid >> 6, lane = tid & 63;
  const int wr = w >> 1, wc = w & 1;
  const int l15 = lane & 15;
  const int g = lane >> 4;
  const int kk = g * 8;
  f32x4 acc[2][2] = {};
  const int sr = tid >> 2;
  const int sk = (tid & 3) * 8;
  const unsigned short* Aptr = A + (size_t)(m0 + sr) * Kp + sk;
  const unsigned short* Bptr = BT + (size_t)(n0 + sr) * Kp + sk;
  for (int k0 = 0; k0 < Kp; k0 += 32) {
    if constexpr (BN_IN) {
      u16x8 a = *(const u16x8*)(Aptr + k0);
      u16x8 ta;
#pragma unroll
      for (int e = 0; e < 8; ++e) {
        const int col = k0 + sk + e;
        float v = fmaf(bf2f(a[e]), sScA[col], sShA[col]);
        ta[e] = f2bf(fmaxf(v, 0.f));
      }
      *(u16x8*)(&As[sr][sk]) = ta;
    } else {
      *(int4*)(&As[sr][sk]) = *(const int4*)(Aptr + k0);
    }
    *(int4*)(&Bs[sr][sk]) = *(const int4*)(Bptr + k0);
    __syncthreads();
    bf16x8 a0  = *(const bf16x8*)(&As[wr * 32 + l15][kk]);
    bf16x8 a1  = *(const bf16x8*)(&As[wr * 32 + 16 + l15][kk]);
    bf16x8 b0  = *(const bf16x8*)(&Bs[wc * 32 + l15][kk]);
    bf16x8 b1v = *(const bf16x8*)(&Bs[wc * 32 + 16 + l15][kk]);
    acc[0][0] = __builtin_amdgcn_mfma_f32_16x16x32_bf16(a0, b0,  acc[0][0], 0, 0, 0);
    acc[0][1] = __builtin_amdgcn_mfma_f32_16x16x32_bf16(a0, b1v, acc[0][1], 0, 0, 0);
    acc[1][0] = __builtin_amdgcn_mfma_f32_16x16x32_bf16(a1, b0,  acc[1][0], 0, 0, 0);
    acc[1][1] = __builtin_amdgcn_mfma_f32_16x16x32_bf16(a1, b1v, acc[1][1], 0, 0, 0);
    __syncthreads();
  }

  float s[2] = {0.f, 0.f}, q2[2] = {0.f, 0.f};
  unsigned short vb[2][2][4];
#pragma unroll
  for (int fc = 0; fc < 2; ++fc) {
    float bv = bias[n0 + wc * 32 + fc * 16 + l15];
#pragma unroll
    for (int fr = 0; fr < 2; ++fr)
#pragma unroll
      for (int r = 0; r < 4; ++r) {
        float xv = acc[fr][fc][r] + bv;
        unsigned short h = f2bf(xv);
        vb[fr][fc][r] = h;
        float xq = bf2f(h);          // stats from the stored bf16 values
        s[fc] += xq;
        q2[fc] = fmaf(xq, xq, q2[fc]);
      }
  }
#pragma unroll
  for (int fc = 0; fc < 2; ++fc) {
    s[fc] += __shfl_xor(s[fc], 16, 64);
    s[fc] += __shfl_xor(s[fc], 32, 64);
    q2[fc] += __shfl_xor(q2[fc], 16, 64);
    q2[fc] += __shfl_xor(q2[fc], 32, 64);
  }
  if (lane < 16) {
#pragma unroll
    for (int fc = 0; fc < 2; ++fc) {
      atomicAdd(&sSum[wc * 32 + fc * 16 + lane], s[fc]);
      atomicAdd(&sSq[wc * 32 + fc * 16 + lane], q2[fc]);
    }
  }
  // write pre-activation bf16 while the LDS reduction settles
#pragma unroll
  for (int fc = 0; fc < 2; ++fc) {
    int col = n0 + wc * 32 + fc * 16 + l15;
#pragma unroll
    for (int fr = 0; fr < 2; ++fr)
#pragma unroll
      for (int r = 0; r < 4; ++r) {
        int row = m0 + wr * 32 + fr * 16 + g * 4 + r;
        pre[(size_t)row * OO + col] = vb[fr][fc][r];
      }
  }
  __syncthreads();
  if (tid < 64) {
    atomicAdd(&dsum[n0 + tid], (double)sSum[tid]);
    atomicAdd(&dsumsq[n0 + tid], (double)sSq[tid]);
  }
}

// Streams pre (bf16 [MM][256]) -> BN -> f32 out. Each block derives
// scale/shift from the global double stats itself.
__global__ __launch_bounds__(256) void bn_apply(const unsigned short* __restrict__ pre,
                                                const double* __restrict__ dsum,
                                                const double* __restrict__ dsumsq,
                                                const float* __restrict__ gamma,
                                                const float* __restrict__ beta,
                                                float* __restrict__ outp) {
  __shared__ float sSc[256], sSh[256];
  const int tid = threadIdx.x;
  {
    double mu = dsum[tid] * (1.0 / 16384.0);
    double var = dsumsq[tid] * (1.0 / 16384.0) - mu * mu;
    float sc = (float)((double)gamma[tid] / sqrt(var + 1e-5));
    sSc[tid] = sc;
    sSh[tid] = beta[tid] - (float)mu * sc;
  }
  __syncthreads();
  const int cg = (tid & 31) * 8;
  float sc[8], sh[8];
#pragma unroll
  for (int j = 0; j < 8; ++j) { sc[j] = sSc[cg + j]; sh[j] = sSh[cg + j]; }
  const int r0 = blockIdx.x * 32 + (tid >> 5);
#pragma unroll
  for (int it = 0; it < 4; ++it) {
    const int row = r0 + it * 8;
    u16x8 v = *(const u16x8*)(pre + (size_t)row * OO + cg);
    float4 o0, o1;
    o0.x = fmaf(bf2f(v[0]), sc[0], sh[0]);
    o0.y = fmaf(bf2f(v[1]), sc[1], sh[1]);
    o0.z = fmaf(bf2f(v[2]), sc[2], sh[2]);
    o0.w = fmaf(bf2f(v[3]), sc[3], sh[3]);
    o1.x = fmaf(bf2f(v[4]), sc[4], sh[4]);
    o1.y = fmaf(bf2f(v[5]), sc[5], sh[5]);
    o1.z = fmaf(bf2f(v[6]), sc[6], sh[6]);
    o1.w = fmaf(bf2f(v[7]), sc[7], sh[7]);
    float* op = outp + (size_t)row * OO + cg;
    *(float4*)op = o0;
    *(float4*)(op + 4) = o1;
  }
}

}  // namespace

extern "C" void kernel_launch(void* const* d_in, const int* in_sizes, int n_in,
                              void* d_out, int out_size, void* d_ws, size_t ws_size,
                              hipStream_t stream) {
  const float* x   = (const float*)d_in[0];
  const float* pos = (const float*)d_in[1];
  const float* W1  = (const float*)d_in[2];
  const float* b1  = (const float*)d_in[3];
  const float* g1  = (const float*)d_in[4];
  const float* be1 = (const float*)d_in[5];
  const float* W2  = (const float*)d_in[6];
  const float* b2  = (const float*)d_in[7];
  const float* g2  = (const float*)d_in[8];
  const float* be2 = (const float*)d_in[9];

  char* ws = (char*)d_ws;
  double* stats        = (double*)(ws + 0);                  // 1024 doubles
  unsigned short* avg  = (unsigned short*)(ws + 1060864);    // 16384*160 bf16
  unsigned short* W1T  = (unsigned short*)(ws + 6303744);    // 256*160 bf16
  unsigned short* W2T  = (unsigned short*)(ws + 6385664);    // 256*256 bf16
  unsigned short* pre1 = (unsigned short*)(ws + 6516736);    // 16384*256 bf16
  unsigned short* pre2 = (unsigned short*)(ws + 14905344);   // 16384*256 bf16

  knn_gather<<<NKNN + 209, 256, 0, stream>>>(pos, x, avg, W1, W2, W1T, W2T, stats);
  gemm_stats<false><<<dim3(MM / 64, OO / 64), 256, 0, stream>>>(
      avg, W1T, b1, nullptr, nullptr, nullptr, nullptr,
      stats, stats + 256, pre1, K1);
  gemm_stats<true><<<dim3(MM / 64, OO / 64), 256, 0, stream>>>(
      pre1, W2T, b2, stats, stats + 256, g1, be1,
      stats + 512, stats + 768, pre2, OO);
  bn_apply<<<MM / 32, 256, 0, stream>>>(pre2, stats + 512, stats + 768, g2, be2, (float*)d_out);
}

// Round 9
// 70.093 us; speedup vs baseline: 2.3166x; 1.1939x over previous
//
#include <hip/hip_runtime.h>
#include <hip/hip_bf16.h>

namespace {

constexpr int BB = 8;
constexpr int NPTS = 2048;
constexpr int CC = 128;
constexpr int MM = BB * NPTS;   // 16384
constexpr int OO = 256;
constexpr int K1 = 160;         // 131 padded to multiple of 32
constexpr int NKNN = MM / 4;    // 4096 knn blocks (4 queries each)

typedef __attribute__((ext_vector_type(8))) short bf16x8;
typedef __attribute__((ext_vector_type(8))) unsigned short u16x8;
typedef __attribute__((ext_vector_type(4))) float f32x4;

__device__ __forceinline__ unsigned short f2bf(float v) {
  unsigned u = __builtin_bit_cast(unsigned, v);
  u += 0x7FFFu + ((u >> 16) & 1u);
  return (unsigned short)(u >> 16);
}

__device__ __forceinline__ float bf2f(unsigned short s) {
  unsigned u = (unsigned)s << 16;
  return __builtin_bit_cast(float, u);
}

__device__ __forceinline__ unsigned long long shflxor64(unsigned long long v, int m) {
  int lo = __shfl_xor((int)(unsigned)v, m, 64);
  int hi = __shfl_xor((int)(unsigned)(v >> 32), m, 64);
  return ((unsigned long long)(unsigned)hi << 32) | (unsigned)lo;
}

// Cheap xor-partner exchange: DPP for xor1/2, ds_swizzle for xor4/8/16, shfl for 32.
template <int J>
__device__ __forceinline__ int partner32i(int v) {
  if constexpr (J == 1)  return __builtin_amdgcn_mov_dpp(v, 0xB1, 0xF, 0xF, true);
  else if constexpr (J == 2)  return __builtin_amdgcn_mov_dpp(v, 0x4E, 0xF, 0xF, true);
  else if constexpr (J == 4)  return __builtin_amdgcn_ds_swizzle(v, 0x101F);
  else if constexpr (J == 8)  return __builtin_amdgcn_ds_swizzle(v, 0x201F);
  else if constexpr (J == 16) return __builtin_amdgcn_ds_swizzle(v, 0x401F);
  else return __shfl_xor(v, 32, 64);
}

template <int J>
__device__ __forceinline__ unsigned long long partner64(unsigned long long v) {
  int lo = partner32i<J>((int)(unsigned)v);
  int hi = partner32i<J>((int)(unsigned)(v >> 32));
  return ((unsigned long long)(unsigned)hi << 32) | (unsigned)lo;
}

__device__ __forceinline__ unsigned long long bitonic_sort64(unsigned long long key, int lane) {
#define BSTAGE(K, J)                                                        \
  {                                                                         \
    unsigned long long o = partner64<J>(key);                               \
    bool keepMin = (((lane & (K)) == 0) == ((lane & (J)) == 0));            \
    bool less = key < o;                                                    \
    key = (less == keepMin) ? key : o;                                      \
  }
  BSTAGE(2, 1)
  BSTAGE(4, 2) BSTAGE(4, 1)
  BSTAGE(8, 4) BSTAGE(8, 2) BSTAGE(8, 1)
  BSTAGE(16, 8) BSTAGE(16, 4) BSTAGE(16, 2) BSTAGE(16, 1)
  BSTAGE(32, 16) BSTAGE(32, 8) BSTAGE(32, 4) BSTAGE(32, 2) BSTAGE(32, 1)
  BSTAGE(64, 32) BSTAGE(64, 16) BSTAGE(64, 8) BSTAGE(64, 4) BSTAGE(64, 2) BSTAGE(64, 1)
#undef BSTAGE
  return key;
}

// u32 bitonic sort (for the distance-bits threshold pass: half the cost of u64)
__device__ __forceinline__ unsigned bitonic_sort64_u32(unsigned key, int lane) {
#define BSTAGE32(K, J)                                                      \
  {                                                                         \
    unsigned o = (unsigned)partner32i<J>((int)key);                         \
    bool keepMin = (((lane & (K)) == 0) == ((lane & (J)) == 0));            \
    bool less = key < o;                                                    \
    key = (less == keepMin) ? key : o;                                      \
  }
  BSTAGE32(2, 1)
  BSTAGE32(4, 2) BSTAGE32(4, 1)
  BSTAGE32(8, 4) BSTAGE32(8, 2) BSTAGE32(8, 1)
  BSTAGE32(16, 8) BSTAGE32(16, 4) BSTAGE32(16, 2) BSTAGE32(16, 1)
  BSTAGE32(32, 16) BSTAGE32(32, 8) BSTAGE32(32, 4) BSTAGE32(32, 2) BSTAGE32(32, 1)
  BSTAGE32(64, 32) BSTAGE32(64, 16) BSTAGE32(64, 8) BSTAGE32(64, 4) BSTAGE32(64, 2) BSTAGE32(64, 1)
#undef BSTAGE32
  return key;
}

__device__ __forceinline__ unsigned long long u64min(unsigned long long a, unsigned long long b) {
  return a < b ? a : b;
}

// Blocks [0,4096): exact 16-NN (1 wave/query, 4 queries/block) fused with the
// neighbor gather+average. Block->(batch = p&7) XCD-affinity remap keeps each
// batch's x-slice resident in ONE XCD L2. Pass 1 tracks per-lane min DISTANCE
// BITS only (u32, valid: d>=0 -> bit order == float order); Td = 16th smallest
// lane-min via u32 bitonic. Survivors (d_bits <= Td, >=16 guaranteed) carry
// full u64 (d,idx) keys into the final exact u64 sort -> selection identical
// to jax.lax.top_k (incl. index tiebreak). dvals cached in regs; no vmem in
// the hot loop. Blocks [4096,4304): weight transpose. Block 4304: stats zero.
__global__ __launch_bounds__(256, 6) void knn_gather(const float* __restrict__ pos,
                                                     const float* __restrict__ x,
                                                     unsigned short* __restrict__ avg,
                                                     const float* __restrict__ W1,
                                                     const float* __restrict__ W2,
                                                     unsigned short* __restrict__ W1T,
                                                     unsigned short* __restrict__ W2T,
                                                     double* __restrict__ stats) {
#pragma clang fp contract(off)
  __shared__ float2 pxy[NPTS];
  __shared__ float pzz[NPTS];
  __shared__ unsigned long long sbuf[4][64];
  const int tid = threadIdx.x;
  if (blockIdx.x >= NKNN) {
    const int i2 = blockIdx.x - NKNN;
    if (i2 == 208) {
      for (int i = tid; i < 1024; i += 256) stats[i] = 0.0;
      return;
    }
    const int i = i2 * 512 + (tid << 1);   // 208 blocks x 512 cover 106496
#pragma unroll
    for (int e = 0; e < 2; ++e) {
      const int ii = i + e;
      if (ii < 256 * K1) {
        const int n = ii / K1, k = ii - n * K1;
        W1T[ii] = f2bf(k < 131 ? W1[k * 256 + n] : 0.f);
      } else {
        const int j = ii - 256 * K1;
        const int n = j >> 8, k = j & 255;
        W2T[j] = f2bf(W2[k * 256 + n]);
      }
    }
    return;
  }
  const int b = blockIdx.x & 7;            // XCD-affinity: batch == bid%8
  const int qblk = blockIdx.x >> 3;        // 0..511
  const float* pb = pos + (size_t)b * NPTS * 3;
  for (int i = tid; i < NPTS; i += 256) {
    pxy[i] = make_float2(pb[3 * i], pb[3 * i + 1]);
    pzz[i] = pb[3 * i + 2];
  }
  __syncthreads();
  const int lane = tid & 63;
  const int wid = tid >> 6;
  const int q = (qblk << 2) + wid;         // query within batch
  const float2 qxy = pxy[q];
  const float qz = pzz[q];

  float dvals[32];
  unsigned mind = 0xFFFFFFFFu;             // f32 bits of per-lane min distance
#pragma unroll
  for (int t = 0; t < 32; ++t) {
    const int j = lane + (t << 6);
    float2 pp = pxy[j];
    float dx = qxy.x - pp.x;
    float dy = qxy.y - pp.y;
    float dz = qz - pzz[j];
    float d = ((dx * dx) + (dy * dy)) + (dz * dz);  // reference order, no fma
    dvals[t] = d;
    unsigned db = __float_as_uint(d);
    mind = db < mind ? db : mind;
  }
  unsigned sk32 = bitonic_sort64_u32(mind, lane);
  const unsigned Td = (unsigned)__builtin_amdgcn_readlane((int)sk32, 15);

  // Pass 2: compact survivors (d_bits <= Td) with full u64 keys into LDS.
  unsigned long long* buf = sbuf[wid];
  int base = 0;
#pragma unroll
  for (int t = 0; t < 32; ++t) {
    unsigned db = __float_as_uint(dvals[t]);
    bool surv = db <= Td;
    unsigned long long mask = __ballot(surv);
    if (surv) {
      int off = __popcll(mask & ((1ull << lane) - 1ull));
      if (base + off < 64)
        buf[base + off] = ((unsigned long long)db << 11) | (unsigned)(lane + (t << 6));
    }
    base += (int)__popcll(mask);
  }

  int myidx = 0;   // lane k (k<16) holds the k-th neighbor index
  if (base <= 64) {
    // common path (P ~ 1): full exact u64 sort of survivors
    unsigned long long key = (lane < base) ? buf[lane] : ~0ull;
    key = bitonic_sort64(key, lane);
    if (lane < 16) myidx = (int)(key & 2047ull);
  } else {
    // ~never: exact extraction from cached distances, no buffer needed
    unsigned long long prev = 0;
    for (int o = 0; o < 16; ++o) {
      unsigned long long m = ~0ull;
#pragma unroll
      for (int t = 0; t < 32; ++t) {
        unsigned long long key =
            ((unsigned long long)__float_as_uint(dvals[t]) << 11) | (unsigned)(lane + (t << 6));
        if (o == 0 || key > prev) m = u64min(m, key);
      }
#pragma unroll
      for (int off = 32; off > 0; off >>= 1) m = u64min(m, shflxor64(m, off));
      if (lane == o) myidx = (int)(m & 2047ull);
      prev = m;
    }
  }

  // ---- fused gather+average (indices broadcast via readlane, SALU-cheap) ----
  const float* xb = x + (size_t)b * NPTS * CC;
  float ax = 0.f, ay = 0.f;
  int idxs[16];
#pragma unroll
  for (int k = 0; k < 16; ++k) {
    idxs[k] = __builtin_amdgcn_readlane(myidx, k);
    float2 v = *(const float2*)(xb + (size_t)idxs[k] * CC + lane * 2);
    ax += v.x;
    ay += v.y;
  }
  const size_t p = (size_t)b * NPTS + q;
  unsigned short h0 = f2bf(ax * 0.0625f);
  unsigned short h1 = f2bf(ay * 0.0625f);
  *(unsigned*)(avg + p * K1 + lane * 2) = (unsigned)h0 | ((unsigned)h1 << 16);
  if (lane < 32) {
    unsigned short o = 0;
    if (lane < 3) {
      float v = 0.f;
#pragma unroll
      for (int k = 0; k < 16; ++k) v += pb[idxs[k] * 3 + lane];
      o = f2bf(v * 0.0625f);
    }
    avg[p * K1 + 128 + lane] = o;
  }
}

// GEMM + bias; per-column sum/sumsq -> global doubles; writes pre-act bf16.
// BN_IN: applies layer-1 BN+ReLU to A elements during LDS staging (values
// bit-identical to a separate bn_apply pass).
template <bool BN_IN>
__global__ __launch_bounds__(256) void gemm_stats(
    const unsigned short* __restrict__ A, const unsigned short* __restrict__ BT,
    const float* __restrict__ bias,
    const double* __restrict__ dsumIn, const double* __restrict__ dsumsqIn,
    const float* __restrict__ gIn, const float* __restrict__ beIn,
    double* __restrict__ dsum, double* __restrict__ dsumsq,
    unsigned short* __restrict__ pre, int Kp) {
  __shared__ __align__(16) unsigned short As[64][56];
  __shared__ __align__(16) unsigned short Bs[64][56];
  __shared__ float sSum[64], sSq[64];
  __shared__ float sScA[256], sShA[256];
  const int tid = threadIdx.x;
  if (tid < 64) { sSum[tid] = 0.f; sSq[tid] = 0.f; }
  if constexpr (BN_IN) {
    double mu = dsumIn[tid] * (1.0 / 16384.0);
    double var = dsumsqIn[tid] * (1.0 / 16384.0) - mu * mu;
    float sc = (float)((double)gIn[tid] / sqrt(var + 1e-5));
    sScA[tid] = sc;
    sShA[tid] = beIn[tid] - (float)mu * sc;
    __syncthreads();
  }
  const int m0 = blockIdx.x * 64;
  const int n0 = blockIdx.y * 64;
  const int w = tid >> 6, lane = tid & 63;
  const int wr = w >> 1, wc = w & 1;
  const int l15 = lane & 15;
  const int g = lane >> 4;
  const int kk = g * 8;
  f32x4 acc[2][2] = {};
  const int sr = tid >> 2;
  const int sk = (tid & 3) * 8;
  const unsigned short* Aptr = A + (size_t)(m0 + sr) * Kp + sk;
  const unsigned short* Bptr = BT + (size_t)(n0 + sr) * Kp + sk;
  for (int k0 = 0; k0 < Kp; k0 += 32) {
    if constexpr (BN_IN) {
      u16x8 a = *(const u16x8*)(Aptr + k0);
      u16x8 ta;
#pragma unroll
      for (int e = 0; e < 8; ++e) {
        const int col = k0 + sk + e;
        float v = fmaf(bf2f(a[e]), sScA[col], sShA[col]);
        ta[e] = f2bf(fmaxf(v, 0.f));
      }
      *(u16x8*)(&As[sr][sk]) = ta;
    } else {
      *(int4*)(&As[sr][sk]) = *(const int4*)(Aptr + k0);
    }
    *(int4*)(&Bs[sr][sk]) = *(const int4*)(Bptr + k0);
    __syncthreads();
    bf16x8 a0  = *(const bf16x8*)(&As[wr * 32 + l15][kk]);
    bf16x8 a1  = *(const bf16x8*)(&As[wr * 32 + 16 + l15][kk]);
    bf16x8 b0  = *(const bf16x8*)(&Bs[wc * 32 + l15][kk]);
    bf16x8 b1v = *(const bf16x8*)(&Bs[wc * 32 + 16 + l15][kk]);
    acc[0][0] = __builtin_amdgcn_mfma_f32_16x16x32_bf16(a0, b0,  acc[0][0], 0, 0, 0);
    acc[0][1] = __builtin_amdgcn_mfma_f32_16x16x32_bf16(a0, b1v, acc[0][1], 0, 0, 0);
    acc[1][0] = __builtin_amdgcn_mfma_f32_16x16x32_bf16(a1, b0,  acc[1][0], 0, 0, 0);
    acc[1][1] = __builtin_amdgcn_mfma_f32_16x16x32_bf16(a1, b1v, acc[1][1], 0, 0, 0);
    __syncthreads();
  }

  float s[2] = {0.f, 0.f}, q2[2] = {0.f, 0.f};
  unsigned short vb[2][2][4];
#pragma unroll
  for (int fc = 0; fc < 2; ++fc) {
    float bv = bias[n0 + wc * 32 + fc * 16 + l15];
#pragma unroll
    for (int fr = 0; fr < 2; ++fr)
#pragma unroll
      for (int r = 0; r < 4; ++r) {
        float xv = acc[fr][fc][r] + bv;
        unsigned short h = f2bf(xv);
        vb[fr][fc][r] = h;
        float xq = bf2f(h);          // stats from the stored bf16 values
        s[fc] += xq;
        q2[fc] = fmaf(xq, xq, q2[fc]);
      }
  }
#pragma unroll
  for (int fc = 0; fc < 2; ++fc) {
    s[fc] += __shfl_xor(s[fc], 16, 64);
    s[fc] += __shfl_xor(s[fc], 32, 64);
    q2[fc] += __shfl_xor(q2[fc], 16, 64);
    q2[fc] += __shfl_xor(q2[fc], 32, 64);
  }
  if (lane < 16) {
#pragma unroll
    for (int fc = 0; fc < 2; ++fc) {
      atomicAdd(&sSum[wc * 32 + fc * 16 + lane], s[fc]);
      atomicAdd(&sSq[wc * 32 + fc * 16 + lane], q2[fc]);
    }
  }
  // write pre-activation bf16 while the LDS reduction settles
#pragma unroll
  for (int fc = 0; fc < 2; ++fc) {
    int col = n0 + wc * 32 + fc * 16 + l15;
#pragma unroll
    for (int fr = 0; fr < 2; ++fr)
#pragma unroll
      for (int r = 0; r < 4; ++r) {
        int row = m0 + wr * 32 + fr * 16 + g * 4 + r;
        pre[(size_t)row * OO + col] = vb[fr][fc][r];
      }
  }
  __syncthreads();
  if (tid < 64) {
    atomicAdd(&dsum[n0 + tid], (double)sSum[tid]);
    atomicAdd(&dsumsq[n0 + tid], (double)sSq[tid]);
  }
}

// Streams pre (bf16 [MM][256]) -> BN -> f32 out. Each block derives
// scale/shift from the global double stats itself.
__global__ __launch_bounds__(256) void bn_apply(const unsigned short* __restrict__ pre,
                                                const double* __restrict__ dsum,
                                                const double* __restrict__ dsumsq,
                                                const float* __restrict__ gamma,
                                                const float* __restrict__ beta,
                                                float* __restrict__ outp) {
  __shared__ float sSc[256], sSh[256];
  const int tid = threadIdx.x;
  {
    double mu = dsum[tid] * (1.0 / 16384.0);
    double var = dsumsq[tid] * (1.0 / 16384.0) - mu * mu;
    float sc = (float)((double)gamma[tid] / sqrt(var + 1e-5));
    sSc[tid] = sc;
    sSh[tid] = beta[tid] - (float)mu * sc;
  }
  __syncthreads();
  const int cg = (tid & 31) * 8;
  float sc[8], sh[8];
#pragma unroll
  for (int j = 0; j < 8; ++j) { sc[j] = sSc[cg + j]; sh[j] = sSh[cg + j]; }
  const int r0 = blockIdx.x * 32 + (tid >> 5);
#pragma unroll
  for (int it = 0; it < 4; ++it) {
    const int row = r0 + it * 8;
    u16x8 v = *(const u16x8*)(pre + (size_t)row * OO + cg);
    float4 o0, o1;
    o0.x = fmaf(bf2f(v[0]), sc[0], sh[0]);
    o0.y = fmaf(bf2f(v[1]), sc[1], sh[1]);
    o0.z = fmaf(bf2f(v[2]), sc[2], sh[2]);
    o0.w = fmaf(bf2f(v[3]), sc[3], sh[3]);
    o1.x = fmaf(bf2f(v[4]), sc[4], sh[4]);
    o1.y = fmaf(bf2f(v[5]), sc[5], sh[5]);
    o1.z = fmaf(bf2f(v[6]), sc[6], sh[6]);
    o1.w = fmaf(bf2f(v[7]), sc[7], sh[7]);
    float* op = outp + (size_t)row * OO + cg;
    *(float4*)op = o0;
    *(float4*)(op + 4) = o1;
  }
}

}  // namespace

extern "C" void kernel_launch(void* const* d_in, const int* in_sizes, int n_in,
                              void* d_out, int out_size, void* d_ws, size_t ws_size,
                              hipStream_t stream) {
  const float* x   = (const float*)d_in[0];
  const float* pos = (const float*)d_in[1];
  const float* W1  = (const float*)d_in[2];
  const float* b1  = (const float*)d_in[3];
  const float* g1  = (const float*)d_in[4];
  const float* be1 = (const float*)d_in[5];
  const float* W2  = (const float*)d_in[6];
  const float* b2  = (const float*)d_in[7];
  const float* g2  = (const float*)d_in[8];
  const float* be2 = (const float*)d_in[9];

  char* ws = (char*)d_ws;
  double* stats        = (double*)(ws + 0);                  // 1024 doubles
  unsigned short* avg  = (unsigned short*)(ws + 1060864);    // 16384*160 bf16
  unsigned short* W1T  = (unsigned short*)(ws + 6303744);    // 256*160 bf16
  unsigned short* W2T  = (unsigned short*)(ws + 6385664);    // 256*256 bf16
  unsigned short* pre1 = (unsigned short*)(ws + 6516736);    // 16384*256 bf16
  unsigned short* pre2 = (unsigned short*)(ws + 14905344);   // 16384*256 bf16

  knn_gather<<<NKNN + 209, 256, 0, stream>>>(pos, x, avg, W1, W2, W1T, W2T, stats);
  gemm_stats<false><<<dim3(MM / 64, OO / 64), 256, 0, stream>>>(
      avg, W1T, b1, nullptr, nullptr, nullptr, nullptr,
      stats, stats + 256, pre1, K1);
  gemm_stats<true><<<dim3(MM / 64, OO / 64), 256, 0, stream>>>(
      pre1, W2T, b2, stats, stats + 256, g1, be1,
      stats + 512, stats + 768, pre2, OO);
  bn_apply<<<MM / 32, 256, 0, stream>>>(pre2, stats + 512, stats + 768, g2, be2, (float*)d_out);
}